// Round 12
// baseline (27.540 us; speedup 1.0000x reference)
//
#include <hip/hip_runtime.h>

// DSSIM loss: y_pred, y_true [8,3,512,512] fp32 -> scalar mean DSSIM.
// R12 = R10 body + R11's Q-stat merge + memset/atomicAdd tail.
//  - wave = 16 col-lanes x 4 row-groups (64 cols x 16 rows); thread = 4x4 px;
//    rows loaded once (1.125x bytes); vertical exchange shfl(16); horizontal
//    halo shfl(1) + small LDS edge patch. Preload-all-24 straight-line.
//  - stats: T, P, Q=Sum(t^2+p^2), TP (var_t+var_p is all SSIM needs).
//  - tail: memset(out) node (overlaps launch ramp) + one fp32 atomicAdd per
//    block (order noise ~1e-7 << 9.9e-3 threshold). No reduce kernel node
//    (R11 showed spin-fusion costs +2us; reduce node costs ~2-3us).

#define N_IMG 8
#define C_CH 3
#define H_DIM 512
#define W_DIM 512
#define BLOCK 512
#define GRID 256   // 8 img x 32 bands of 16 rows; block = band x 512 cols

__global__ __launch_bounds__(BLOCK, 2) void dssim_fused(
        const float* __restrict__ yp,
        const float* __restrict__ yt,
        float* __restrict__ out) {
    const int tid  = threadIdx.x;
    const int lane = tid & 63;
    const int wc   = tid >> 6;          // wave = 64-col slab, 0..7
    const int rg   = lane >> 4;         // row-group within wave, 0..3
    const int cl   = lane & 15;         // col-thread within row-group
    const int b    = blockIdx.x;
    const int n    = b >> 5;            // image
    const int vb   = b & 31;            // 16-row band within image
    const int h0   = (vb << 4) + (rg << 2);   // first owned row
    const int w0   = (wc << 6) + (cl << 2);   // first owned col

    // ---- preload owned rows: 24 float4, straight-line ----
    float4 T[3][4], P[3][4];
    #pragma unroll
    for (int c = 0; c < C_CH; ++c) {
        const size_t rb = ((size_t)((n * C_CH + c) * H_DIM + h0)) * W_DIM + w0;
        #pragma unroll
        for (int r = 0; r < 4; ++r) {
            T[c][r] = *(const float4*)(yt + rb + (size_t)r * W_DIM);
            P[c][r] = *(const float4*)(yp + rb + (size_t)r * W_DIM);
        }
    }

    // ---- band-boundary halo rowsums (rg0: row h0-1, rg3: row h0+4) ----
    // stats: 0=T 1=P 2=Q(=tt+pp) 3=TP
    float rH[4][4];
    #pragma unroll
    for (int s = 0; s < 4; ++s)
        #pragma unroll
        for (int j = 0; j < 4; ++j) rH[s][j] = 0.f;
    {
        const bool need = (rg == 0) ? (vb != 0) : ((rg == 3) ? (vb != 31) : false);
        if (need) {
            const int hh = (rg == 0) ? (h0 - 1) : (h0 + 4);
            #pragma unroll
            for (int c = 0; c < C_CH; ++c) {
                const size_t a = ((size_t)((n * C_CH + c) * H_DIM + hh)) * W_DIM + w0;
                const float4 t = *(const float4*)(yt + a);
                const float4 p = *(const float4*)(yp + a);
                const float tv[4] = {t.x, t.y, t.z, t.w};
                const float pv[4] = {p.x, p.y, p.z, p.w};
                #pragma unroll
                for (int j = 0; j < 4; ++j) {
                    rH[0][j] += tv[j];
                    rH[1][j] += pv[j];
                    rH[2][j] = fmaf(tv[j], tv[j], rH[2][j]);
                    rH[2][j] = fmaf(pv[j], pv[j], rH[2][j]);
                    rH[3][j] = fmaf(tv[j], pv[j], rH[3][j]);
                }
            }
        }
    }

    // ---- per-row column sums for owned rows ----
    float rS[4][4][4];   // [row][stat][col]
    #pragma unroll
    for (int r = 0; r < 4; ++r)
        #pragma unroll
        for (int s = 0; s < 4; ++s)
            #pragma unroll
            for (int j = 0; j < 4; ++j) rS[r][s][j] = 0.f;

    #pragma unroll
    for (int c = 0; c < C_CH; ++c) {
        #pragma unroll
        for (int r = 0; r < 4; ++r) {
            const float tv[4] = {T[c][r].x, T[c][r].y, T[c][r].z, T[c][r].w};
            const float pv[4] = {P[c][r].x, P[c][r].y, P[c][r].z, P[c][r].w};
            #pragma unroll
            for (int j = 0; j < 4; ++j) {
                rS[r][0][j] += tv[j];
                rS[r][1][j] += pv[j];
                rS[r][2][j] = fmaf(tv[j], tv[j], rS[r][2][j]);
                rS[r][2][j] = fmaf(pv[j], pv[j], rS[r][2][j]);
                rS[r][3][j] = fmaf(tv[j], pv[j], rS[r][3][j]);
            }
        }
    }

    // ---- vertical rowsum exchange via intra-wave shfl (no LDS, no sync) ----
    float rPrev[4][4], rNext[4][4];
    #pragma unroll
    for (int s = 0; s < 4; ++s)
        #pragma unroll
        for (int j = 0; j < 4; ++j) {
            const float up = __shfl_up(rS[3][s][j], 16);    // rg-1's bottom row
            const float dn = __shfl_down(rS[0][s][j], 16);  // rg+1's top row
            rPrev[s][j] = (rg == 0) ? rH[s][j] : up;
            rNext[s][j] = (rg == 3) ? rH[s][j] : dn;
        }

    // ---- vertical 3-row window sums ----
    float wS[4][4][4];   // [outrow][stat][col]
    #pragma unroll
    for (int s = 0; s < 4; ++s)
        #pragma unroll
        for (int j = 0; j < 4; ++j) {
            const float r01 = rS[0][s][j] + rS[1][s][j];
            const float r12 = rS[1][s][j] + rS[2][s][j];
            const float r23 = rS[2][s][j] + rS[3][s][j];
            wS[0][s][j] = rPrev[s][j] + r01;
            wS[1][s][j] = r01 + rS[2][s][j];
            wS[2][s][j] = r12 + rS[3][s][j];
            wS[3][s][j] = r23 + rNext[s][j];
        }

    // ---- cross-wave horizontal edge publish ----
    __shared__ float eL[8][4][4][4];   // [wc][rg][o][s]
    __shared__ float eR[8][4][4][4];
    if (cl == 0) {
        #pragma unroll
        for (int o = 0; o < 4; ++o)
            #pragma unroll
            for (int s = 0; s < 4; ++s) eL[wc][rg][o][s] = wS[o][s][0];
    }
    if (cl == 15) {
        #pragma unroll
        for (int o = 0; o < 4; ++o)
            #pragma unroll
            for (int s = 0; s < 4; ++s) eR[wc][rg][o][s] = wS[o][s][3];
    }
    __syncthreads();

    // ---- horizontal halo via shfl(+-1) + edge patch ----
    float lh[4][4], rh[4][4];
    #pragma unroll
    for (int o = 0; o < 4; ++o)
        #pragma unroll
        for (int s = 0; s < 4; ++s) {
            lh[o][s] = __shfl_up(wS[o][s][3], 1);
            rh[o][s] = __shfl_down(wS[o][s][0], 1);
        }
    if (cl == 0) {
        #pragma unroll
        for (int o = 0; o < 4; ++o)
            #pragma unroll
            for (int s = 0; s < 4; ++s)
                lh[o][s] = (wc > 0) ? eR[wc - 1][rg][o][s] : 0.f;
    }
    if (cl == 15) {
        #pragma unroll
        for (int o = 0; o < 4; ++o)
            #pragma unroll
            for (int s = 0; s < 4; ++s)
                rh[o][s] = (wc < 7) ? eL[wc + 1][rg][o][s] : 0.f;
    }

    // ---- SSIM epilogue (horizontal prefix sums) ----
    const float C1f = 1.0e-4f;
    const float C2f = 9.0e-4f;
    const float inv_n = 1.f / 27.f;
    const float inv_v = 1.f / 26.f;

    float lsum = 0.f;
    #pragma unroll
    for (int o = 0; o < 4; ++o) {
        float hw[4][4];
        #pragma unroll
        for (int s = 0; s < 4; ++s) {
            const float a0 = wS[o][s][0], a1 = wS[o][s][1];
            const float a2 = wS[o][s][2], a3 = wS[o][s][3];
            const float s01 = a0 + a1, s12 = a1 + a2, s23 = a2 + a3;
            hw[s][0] = lh[o][s] + s01;
            hw[s][1] = s01 + a2;
            hw[s][2] = s12 + a3;
            hw[s][3] = s23 + rh[o][s];
        }
        #pragma unroll
        for (int k = 0; k < 4; ++k) {
            const float st  = hw[0][k];
            const float sp  = hw[1][k];
            const float sq  = hw[2][k];
            const float stp = hw[3][k];

            const float ut = st * inv_n;
            const float up = sp * inv_n;
            const float varsum = (sq - (st * st + sp * sp) * inv_n) * inv_v;
            const float cov    = stp * inv_n - ut * up;

            const float num = (2.f * ut * up + C1f) * (2.f * cov + C2f);
            const float den = (ut * ut + up * up + C1f) * (varsum + C2f);
            lsum = fmaf(-num * __builtin_amdgcn_rcpf(den), 0.5f, lsum + 0.5f);
        }
    }

    // ---- block reduction -> one atomicAdd per block ----
    #pragma unroll
    for (int off = 32; off > 0; off >>= 1)
        lsum += __shfl_down(lsum, off, 64);

    __shared__ float smem[BLOCK / 64];
    if (lane == 0) smem[wc] = lsum;
    __syncthreads();
    if (tid == 0) {
        float s = 0.f;
        #pragma unroll
        for (int i = 0; i < BLOCK / 64; ++i) s += smem[i];
        atomicAdd(out, s * (1.f / (float)(N_IMG * H_DIM * W_DIM)));
    }
}

extern "C" void kernel_launch(void* const* d_in, const int* in_sizes, int n_in,
                              void* d_out, int out_size, void* d_ws, size_t ws_size,
                              hipStream_t stream) {
    const float* yp = (const float*)d_in[0];   // y_pred
    const float* yt = (const float*)d_in[1];   // y_true
    float* out = (float*)d_out;

    hipMemsetAsync(out, 0, sizeof(float) * (size_t)out_size, stream);
    dssim_fused<<<GRID, BLOCK, 0, stream>>>(yp, yt, out);
}

// Round 13
// 19.332 us; speedup vs baseline: 1.4246x; 1.4246x over previous
//
#include <hip/hip_runtime.h>

// DSSIM loss: y_pred, y_true [8,3,512,512] fp32 -> scalar mean DSSIM.
// R13 = R10 structure (2 nodes: partial -> d_ws, reduce kernel; measured
// optimum -- memset+atomic tail costs +7us (R6/R12), spin-fusion +2 (R11),
// coop +35 (R9)) + R12's Q-stat merge (T,P,Q=Sum(t^2+p^2),TP) + slim
// 1-wave float4 reduce kernel.
//  - wave = 16 col-lanes x 4 row-groups (64 cols x 16 rows); thread = 4x4 px;
//    rows loaded once (1.125x delivered bytes); vertical exchange shfl(16);
//    horizontal halo shfl(1) + small LDS edge patch; preload-all-24
//    straight-line loads (R7 lesson: keeps ~24 loads in flight).

#define N_IMG 8
#define C_CH 3
#define H_DIM 512
#define W_DIM 512
#define BLOCK 512
#define GRID 256   // 8 img x 32 bands of 16 rows; block = band x 512 cols

__global__ __launch_bounds__(BLOCK, 2) void dssim_partial(
        const float* __restrict__ yp,
        const float* __restrict__ yt,
        float* __restrict__ ws) {
    const int tid  = threadIdx.x;
    const int lane = tid & 63;
    const int wc   = tid >> 6;          // wave = 64-col slab, 0..7
    const int rg   = lane >> 4;         // row-group within wave, 0..3
    const int cl   = lane & 15;         // col-thread within row-group
    const int b    = blockIdx.x;
    const int n    = b >> 5;            // image
    const int vb   = b & 31;            // 16-row band within image
    const int h0   = (vb << 4) + (rg << 2);   // first owned row
    const int w0   = (wc << 6) + (cl << 2);   // first owned col

    // ---- preload owned rows: 24 float4, straight-line ----
    float4 T[3][4], P[3][4];
    #pragma unroll
    for (int c = 0; c < C_CH; ++c) {
        const size_t rb = ((size_t)((n * C_CH + c) * H_DIM + h0)) * W_DIM + w0;
        #pragma unroll
        for (int r = 0; r < 4; ++r) {
            T[c][r] = *(const float4*)(yt + rb + (size_t)r * W_DIM);
            P[c][r] = *(const float4*)(yp + rb + (size_t)r * W_DIM);
        }
    }

    // ---- band-boundary halo rowsums (rg0: row h0-1, rg3: row h0+4) ----
    // stats: 0=T 1=P 2=Q(=tt+pp) 3=TP
    float rH[4][4];
    #pragma unroll
    for (int s = 0; s < 4; ++s)
        #pragma unroll
        for (int j = 0; j < 4; ++j) rH[s][j] = 0.f;
    {
        const bool need = (rg == 0) ? (vb != 0) : ((rg == 3) ? (vb != 31) : false);
        if (need) {
            const int hh = (rg == 0) ? (h0 - 1) : (h0 + 4);
            #pragma unroll
            for (int c = 0; c < C_CH; ++c) {
                const size_t a = ((size_t)((n * C_CH + c) * H_DIM + hh)) * W_DIM + w0;
                const float4 t = *(const float4*)(yt + a);
                const float4 p = *(const float4*)(yp + a);
                const float tv[4] = {t.x, t.y, t.z, t.w};
                const float pv[4] = {p.x, p.y, p.z, p.w};
                #pragma unroll
                for (int j = 0; j < 4; ++j) {
                    rH[0][j] += tv[j];
                    rH[1][j] += pv[j];
                    rH[2][j] = fmaf(tv[j], tv[j], rH[2][j]);
                    rH[2][j] = fmaf(pv[j], pv[j], rH[2][j]);
                    rH[3][j] = fmaf(tv[j], pv[j], rH[3][j]);
                }
            }
        }
    }

    // ---- per-row column sums for owned rows ----
    float rS[4][4][4];   // [row][stat][col]
    #pragma unroll
    for (int r = 0; r < 4; ++r)
        #pragma unroll
        for (int s = 0; s < 4; ++s)
            #pragma unroll
            for (int j = 0; j < 4; ++j) rS[r][s][j] = 0.f;

    #pragma unroll
    for (int c = 0; c < C_CH; ++c) {
        #pragma unroll
        for (int r = 0; r < 4; ++r) {
            const float tv[4] = {T[c][r].x, T[c][r].y, T[c][r].z, T[c][r].w};
            const float pv[4] = {P[c][r].x, P[c][r].y, P[c][r].z, P[c][r].w};
            #pragma unroll
            for (int j = 0; j < 4; ++j) {
                rS[r][0][j] += tv[j];
                rS[r][1][j] += pv[j];
                rS[r][2][j] = fmaf(tv[j], tv[j], rS[r][2][j]);
                rS[r][2][j] = fmaf(pv[j], pv[j], rS[r][2][j]);
                rS[r][3][j] = fmaf(tv[j], pv[j], rS[r][3][j]);
            }
        }
    }

    // ---- vertical rowsum exchange via intra-wave shfl (no LDS, no sync) ----
    float rPrev[4][4], rNext[4][4];
    #pragma unroll
    for (int s = 0; s < 4; ++s)
        #pragma unroll
        for (int j = 0; j < 4; ++j) {
            const float up = __shfl_up(rS[3][s][j], 16);    // rg-1's bottom row
            const float dn = __shfl_down(rS[0][s][j], 16);  // rg+1's top row
            rPrev[s][j] = (rg == 0) ? rH[s][j] : up;
            rNext[s][j] = (rg == 3) ? rH[s][j] : dn;
        }

    // ---- vertical 3-row window sums ----
    float wS[4][4][4];   // [outrow][stat][col]
    #pragma unroll
    for (int s = 0; s < 4; ++s)
        #pragma unroll
        for (int j = 0; j < 4; ++j) {
            const float r01 = rS[0][s][j] + rS[1][s][j];
            const float r12 = rS[1][s][j] + rS[2][s][j];
            const float r23 = rS[2][s][j] + rS[3][s][j];
            wS[0][s][j] = rPrev[s][j] + r01;
            wS[1][s][j] = r01 + rS[2][s][j];
            wS[2][s][j] = r12 + rS[3][s][j];
            wS[3][s][j] = r23 + rNext[s][j];
        }

    // ---- cross-wave horizontal edge publish ----
    __shared__ float eL[8][4][4][4];   // [wc][rg][o][s]
    __shared__ float eR[8][4][4][4];
    if (cl == 0) {
        #pragma unroll
        for (int o = 0; o < 4; ++o)
            #pragma unroll
            for (int s = 0; s < 4; ++s) eL[wc][rg][o][s] = wS[o][s][0];
    }
    if (cl == 15) {
        #pragma unroll
        for (int o = 0; o < 4; ++o)
            #pragma unroll
            for (int s = 0; s < 4; ++s) eR[wc][rg][o][s] = wS[o][s][3];
    }
    __syncthreads();

    // ---- horizontal halo via shfl(+-1) + edge patch ----
    float lh[4][4], rh[4][4];
    #pragma unroll
    for (int o = 0; o < 4; ++o)
        #pragma unroll
        for (int s = 0; s < 4; ++s) {
            lh[o][s] = __shfl_up(wS[o][s][3], 1);
            rh[o][s] = __shfl_down(wS[o][s][0], 1);
        }
    if (cl == 0) {
        #pragma unroll
        for (int o = 0; o < 4; ++o)
            #pragma unroll
            for (int s = 0; s < 4; ++s)
                lh[o][s] = (wc > 0) ? eR[wc - 1][rg][o][s] : 0.f;
    }
    if (cl == 15) {
        #pragma unroll
        for (int o = 0; o < 4; ++o)
            #pragma unroll
            for (int s = 0; s < 4; ++s)
                rh[o][s] = (wc < 7) ? eL[wc + 1][rg][o][s] : 0.f;
    }

    // ---- SSIM epilogue (horizontal prefix sums) ----
    const float C1f = 1.0e-4f;
    const float C2f = 9.0e-4f;
    const float inv_n = 1.f / 27.f;
    const float inv_v = 1.f / 26.f;

    float lsum = 0.f;
    #pragma unroll
    for (int o = 0; o < 4; ++o) {
        float hw[4][4];
        #pragma unroll
        for (int s = 0; s < 4; ++s) {
            const float a0 = wS[o][s][0], a1 = wS[o][s][1];
            const float a2 = wS[o][s][2], a3 = wS[o][s][3];
            const float s01 = a0 + a1, s12 = a1 + a2, s23 = a2 + a3;
            hw[s][0] = lh[o][s] + s01;
            hw[s][1] = s01 + a2;
            hw[s][2] = s12 + a3;
            hw[s][3] = s23 + rh[o][s];
        }
        #pragma unroll
        for (int k = 0; k < 4; ++k) {
            const float st  = hw[0][k];
            const float sp  = hw[1][k];
            const float sq  = hw[2][k];
            const float stp = hw[3][k];

            const float ut = st * inv_n;
            const float up = sp * inv_n;
            const float varsum = (sq - (st * st + sp * sp) * inv_n) * inv_v;
            const float cov    = stp * inv_n - ut * up;

            const float num = (2.f * ut * up + C1f) * (2.f * cov + C2f);
            const float den = (ut * ut + up * up + C1f) * (varsum + C2f);
            lsum = fmaf(-num * __builtin_amdgcn_rcpf(den), 0.5f, lsum + 0.5f);
        }
    }

    // ---- block reduction -> per-block partial ----
    #pragma unroll
    for (int off = 32; off > 0; off >>= 1)
        lsum += __shfl_down(lsum, off, 64);

    __shared__ float smem[BLOCK / 64];
    if (lane == 0) smem[wc] = lsum;
    __syncthreads();
    if (tid == 0) {
        float s = 0.f;
        #pragma unroll
        for (int i = 0; i < BLOCK / 64; ++i) s += smem[i];
        ws[b] = s;
    }
}

// one wave, float4 reads, no LDS, no syncthreads
__global__ __launch_bounds__(64) void dssim_reduce(
        const float* __restrict__ ws, float* __restrict__ out) {
    const int t = threadIdx.x;
    const float4 v4 = reinterpret_cast<const float4*>(ws)[t];  // 64x4 = 256
    float s = (v4.x + v4.y) + (v4.z + v4.w);
    #pragma unroll
    for (int off = 32; off > 0; off >>= 1)
        s += __shfl_down(s, off, 64);
    if (t == 0)
        out[0] = s * (1.f / (float)(N_IMG * H_DIM * W_DIM));
}

extern "C" void kernel_launch(void* const* d_in, const int* in_sizes, int n_in,
                              void* d_out, int out_size, void* d_ws, size_t ws_size,
                              hipStream_t stream) {
    const float* yp = (const float*)d_in[0];   // y_pred
    const float* yt = (const float*)d_in[1];   // y_true
    float* out = (float*)d_out;
    float* ws  = (float*)d_ws;

    dssim_partial<<<GRID, BLOCK, 0, stream>>>(yp, yt, ws);
    dssim_reduce<<<1, 64, 0, stream>>>(ws, out);
}